// Round 2
// baseline (242.409 us; speedup 1.0000x reference)
//
#include <hip/hip_runtime.h>
#include <hip/hip_bf16.h>

#define DIM   1024
#define HEADS 16
#define DHEAD 64
#define INNER 1024
#define NSEQ  2048
#define NB    2
#define MROWS (NB * NSEQ)   // 4096

typedef __attribute__((ext_vector_type(8))) short    short8;
typedef __attribute__((ext_vector_type(4))) short    short4v;
typedef __attribute__((ext_vector_type(4))) float    floatx4;
typedef __attribute__((ext_vector_type(8))) _Float16 half8;

#define GLOBAL_AS __attribute__((address_space(1)))
#define LDS_AS    __attribute__((address_space(3)))

static __device__ __forceinline__ short f2h(float f) {
  _Float16 h = (_Float16)f;
  return __builtin_bit_cast(short, h);
}

static __device__ __forceinline__ floatx4 mfma16(short8 a, short8 b, floatx4 c) {
  return __builtin_amdgcn_mfma_f32_16x16x32_f16(
      __builtin_bit_cast(half8, a), __builtin_bit_cast(half8, b), c, 0, 0, 0);
}

// ---------------- LayerNorm: x fp32 [4096][1024] -> xn fp16 ----------------
__global__ __launch_bounds__(256) void ln_kernel(const float* __restrict__ x,
                                                 const float* __restrict__ gamma,
                                                 const float* __restrict__ beta,
                                                 short* __restrict__ xn) {
  int row = blockIdx.x;
  int t   = threadIdx.x;
  const float4* xr = reinterpret_cast<const float4*>(x + (size_t)row * DIM);
  float4 v = xr[t];
  float s  = v.x + v.y + v.z + v.w;
  float s2 = v.x * v.x + v.y * v.y + v.z * v.z + v.w * v.w;
#pragma unroll
  for (int off = 1; off < 64; off <<= 1) {
    s  += __shfl_xor(s, off);
    s2 += __shfl_xor(s2, off);
  }
  __shared__ float red[8];
  if ((t & 63) == 0) { red[t >> 6] = s; red[(t >> 6) + 4] = s2; }
  __syncthreads();
  s  = red[0] + red[1] + red[2] + red[3];
  s2 = red[4] + red[5] + red[6] + red[7];
  float mu   = s * (1.0f / DIM);
  float var  = s2 * (1.0f / DIM) - mu * mu;
  float rstd = rsqrtf(var + 1e-5f);
  float4 g  = reinterpret_cast<const float4*>(gamma)[t];
  float4 bb = reinterpret_cast<const float4*>(beta)[t];
  short4v o;
  o.x = f2h((v.x - mu) * rstd * g.x + bb.x);
  o.y = f2h((v.y - mu) * rstd * g.y + bb.y);
  o.z = f2h((v.z - mu) * rstd * g.z + bb.z);
  o.w = f2h((v.w - mu) * rstd * g.w + bb.w);
  reinterpret_cast<short4v*>(xn + (size_t)row * DIM)[t] = o;
}

// ------------- transpose + fp32->fp16: w [K][N] -> wt [N][K] ---------------
__global__ __launch_bounds__(256) void transpose_f16(const float* __restrict__ w,
                                                     short* __restrict__ wt,
                                                     int Kk, int Nn) {
  __shared__ float tile[32][33];
  int n0 = blockIdx.x * 32, k0 = blockIdx.y * 32;
  int tx = threadIdx.x & 31, ty = threadIdx.x >> 5;   // ty in [0,8)
#pragma unroll
  for (int i = 0; i < 32; i += 8)
    tile[ty + i][tx] = w[(size_t)(k0 + ty + i) * Nn + n0 + tx];
  __syncthreads();
#pragma unroll
  for (int i = 0; i < 32; i += 8)
    wt[(size_t)(n0 + ty + i) * Kk + k0 + tx] = f2h(tile[tx][ty + i]);
}

// --------- GEMM: C[M][Nn] = A[M][Kk] * Bt[Nn][Kk]^T, fp16 in ---------------
// 128x128 tile, BK=64, 4 waves, global_load_lds staging, 16x16x32 MFMA.
// F32OUT: write float (final output), else fp16 shorts.
template <bool F32OUT>
__global__ __launch_bounds__(256) void gemm_bt(const short* __restrict__ A,
                                               const short* __restrict__ Bt,
                                               void* __restrict__ Cout,
                                               int Nn, int Kk, float oscale) {
  constexpr int BM = 128, BN = 128, BK = 64;
  __shared__ __attribute__((aligned(16))) short As[BM * BK];
  __shared__ __attribute__((aligned(16))) short Bs[BN * BK];
  int bm = blockIdx.x, bn = blockIdx.y;
  int t = threadIdx.x, lane = t & 63, w = t >> 6;
  int l15 = lane & 15, lhi = lane >> 4;
  int wr = w >> 1, wc = w & 1;
  floatx4 acc[4][4] = {};
  const short* Ag = A + (size_t)bm * BM * Kk;
  const short* Bg = Bt + (size_t)bn * BN * Kk;

  for (int k0 = 0; k0 < Kk; k0 += BK) {
#pragma unroll
    for (int it = 0; it < 4; ++it) {
      int base = it * 256 + w * 64;          // wave-uniform group index
      int idx  = base + lane;
      int row  = idx >> 3, kc = (idx & 7) << 3;
      __builtin_amdgcn_global_load_lds(
          (const GLOBAL_AS unsigned int*)(Ag + (size_t)row * Kk + k0 + kc),
          (LDS_AS unsigned int*)(As + base * 8), 16, 0, 0);
    }
#pragma unroll
    for (int it = 0; it < 4; ++it) {
      int base = it * 256 + w * 64;
      int idx  = base + lane;
      int row  = idx >> 3, kc = (idx & 7) << 3;
      __builtin_amdgcn_global_load_lds(
          (const GLOBAL_AS unsigned int*)(Bg + (size_t)row * Kk + k0 + kc),
          (LDS_AS unsigned int*)(Bs + base * 8), 16, 0, 0);
    }
    __syncthreads();
#pragma unroll
    for (int kc = 0; kc < 2; ++kc) {
      short8 a[4], b[4];
#pragma unroll
      for (int mt = 0; mt < 4; ++mt)
        a[mt] = *reinterpret_cast<const short8*>(
            &As[(wr * 64 + mt * 16 + l15) * BK + lhi * 8 + kc * 32]);
#pragma unroll
      for (int nt = 0; nt < 4; ++nt)
        b[nt] = *reinterpret_cast<const short8*>(
            &Bs[(wc * 64 + nt * 16 + l15) * BK + lhi * 8 + kc * 32]);
#pragma unroll
      for (int mt = 0; mt < 4; ++mt)
#pragma unroll
        for (int nt = 0; nt < 4; ++nt)
          acc[mt][nt] = mfma16(a[mt], b[nt], acc[mt][nt]);
    }
    __syncthreads();
  }

  int row0 = bm * BM + wr * 64;
  int col0 = bn * BN + wc * 64;
#pragma unroll
  for (int mt = 0; mt < 4; ++mt)
#pragma unroll
    for (int nt = 0; nt < 4; ++nt)
#pragma unroll
      for (int r = 0; r < 4; ++r) {
        int row = row0 + mt * 16 + lhi * 4 + r;
        int col = col0 + nt * 16 + l15;
        if (F32OUT)
          ((float*)Cout)[(size_t)row * Nn + col] = acc[mt][nt][r] * oscale;
        else
          ((short*)Cout)[(size_t)row * Nn + col] = f2h(acc[mt][nt][r] * oscale);
      }
}

// ------------------------- causal flash attention --------------------------
// grid (NSEQ/64, HEADS, NB), 256 threads (4 waves x 16 q-rows).
// qs: [B*N][INNER] fp16 (pre-scaled), kvb: [B*N][2*INNER] fp16 (k then v),
// bias fp32 [H][N][N], o: [B*N][INNER] fp16.
__global__ __launch_bounds__(256) void attn_kernel(const short* __restrict__ qs,
                                                   const short* __restrict__ kvb,
                                                   const float* __restrict__ bias,
                                                   short* __restrict__ o) {
  constexpr int LDK = 72;   // padded row stride (shorts)
  __shared__ __attribute__((aligned(16))) short Ks[64 * LDK];
  __shared__ __attribute__((aligned(16))) short Vt[64 * LDK];
  __shared__ __attribute__((aligned(16))) short Ps[64 * LDK];
  int qb = blockIdx.x * 64;
  int h  = blockIdx.y;
  int b  = blockIdx.z;
  int t = threadIdx.x, lane = t & 63, w = t >> 6;
  int l15 = lane & 15, lhi = lane >> 4;

  // Q fragments: wave w owns q-rows [qb + w*16, +16)
  const short* qrow =
      qs + ((size_t)(b * NSEQ + qb + w * 16 + l15)) * INNER + h * DHEAD + lhi * 8;
  short8 qf0 = *reinterpret_cast<const short8*>(qrow);
  short8 qf1 = *reinterpret_cast<const short8*>(qrow + 32);

  float mrow[4], lrow[4];
  floatx4 oacc[4] = {};
#pragma unroll
  for (int r = 0; r < 4; ++r) { mrow[r] = -1e30f; lrow[r] = 0.f; }

  for (int j0 = 0; j0 <= qb; j0 += 64) {
    // ---- stage K (linear, padded) ----
#pragma unroll
    for (int it = 0; it < 2; ++it) {
      int idx = t + it * 256;
      int row = idx >> 3, c = (idx & 7) << 3;
      const short* kp =
          kvb + ((size_t)(b * NSEQ + j0 + row)) * (2 * INNER) + h * DHEAD + c;
      *reinterpret_cast<short8*>(&Ks[row * LDK + c]) =
          *reinterpret_cast<const short8*>(kp);
    }
    // ---- stage V transposed (pair-packed, XOR-swizzled columns) ----
    {
      int rr = (t >> 3) * 2;        // j row pair: 0,2,...,62
      int c  = (t & 7) << 3;        // d base: 0..56
      const short* vp = kvb + ((size_t)(b * NSEQ + j0 + rr)) * (2 * INNER) +
                        INNER + h * DHEAD + c;
      short8 v0 = *reinterpret_cast<const short8*>(vp);
      short8 v1 = *reinterpret_cast<const short8*>(vp + 2 * INNER);
#pragma unroll
      for (int e = 0; e < 8; ++e) {
        int d  = c + e;
        int jj = rr ^ (((d >> 3) & 7) << 3);
        unsigned int pk = (unsigned short)v0[e] |
                          ((unsigned int)(unsigned short)v1[e] << 16);
        *reinterpret_cast<unsigned int*>(&Vt[d * LDK + jj]) = pk;
      }
    }
    __syncthreads();

    // ---- S = Q K^T (per wave: 16 x 64) ----
    floatx4 s[4];
#pragma unroll
    for (int jt = 0; jt < 4; ++jt) { floatx4 z = {0.f, 0.f, 0.f, 0.f}; s[jt] = z; }
#pragma unroll
    for (int jt = 0; jt < 4; ++jt) {
      short8 kf0 = *reinterpret_cast<const short8*>(&Ks[(jt * 16 + l15) * LDK + lhi * 8]);
      short8 kf1 = *reinterpret_cast<const short8*>(&Ks[(jt * 16 + l15) * LDK + lhi * 8 + 32]);
      s[jt] = mfma16(qf0, kf0, s[jt]);
      s[jt] = mfma16(qf1, kf1, s[jt]);
    }

    // ---- bias + causal mask ----
    const float* bb = bias + ((size_t)h * NSEQ + (qb + w * 16)) * NSEQ + j0;
#pragma unroll
    for (int jt = 0; jt < 4; ++jt)
#pragma unroll
      for (int r = 0; r < 4; ++r) {
        int iloc = lhi * 4 + r;          // 0..15 within wave rows
        int jloc = jt * 16 + l15;        // 0..63 within tile
        float sv = s[jt][r] + bb[(size_t)iloc * NSEQ + jloc];
        if (j0 == qb && jloc > w * 16 + iloc) sv = -1e30f;
        s[jt][r] = sv;
      }

    // ---- online softmax (16-lane groups share a row set) ----
#pragma unroll
    for (int r = 0; r < 4; ++r) {
      float mx = fmaxf(fmaxf(s[0][r], s[1][r]), fmaxf(s[2][r], s[3][r]));
#pragma unroll
      for (int off = 1; off < 16; off <<= 1) mx = fmaxf(mx, __shfl_xor(mx, off));
      float mnew = fmaxf(mrow[r], mx);
      float fac  = __expf(mrow[r] - mnew);
      mrow[r] = mnew;
      float ps = 0.f;
#pragma unroll
      for (int jt = 0; jt < 4; ++jt) {
        float p = __expf(s[jt][r] - mnew);
        s[jt][r] = p;
        ps += p;
      }
#pragma unroll
      for (int off = 1; off < 16; off <<= 1) ps += __shfl_xor(ps, off);
      lrow[r] = lrow[r] * fac + ps;
#pragma unroll
      for (int dt = 0; dt < 4; ++dt) oacc[dt][r] *= fac;
    }

    // ---- P -> LDS (C-layout to A-layout transpose) ----
#pragma unroll
    for (int jt = 0; jt < 4; ++jt)
#pragma unroll
      for (int r = 0; r < 4; ++r)
        Ps[(w * 16 + lhi * 4 + r) * LDK + jt * 16 + l15] = f2h(s[jt][r]);
    __syncthreads();

    // ---- O += P V ----
#pragma unroll
    for (int jc = 0; jc < 2; ++jc) {
      short8 pf = *reinterpret_cast<const short8*>(
          &Ps[(w * 16 + l15) * LDK + lhi * 8 + jc * 32]);
#pragma unroll
      for (int dt = 0; dt < 4; ++dt) {
        int dd = dt * 16 + l15;
        int jj = (lhi * 8 + jc * 32) ^ (((dd >> 3) & 7) << 3);
        short8 vf = *reinterpret_cast<const short8*>(&Vt[dd * LDK + jj]);
        oacc[dt] = mfma16(pf, vf, oacc[dt]);
      }
    }
    __syncthreads();
  }

  // ---- epilogue ----
#pragma unroll
  for (int r = 0; r < 4; ++r) lrow[r] = 1.f / lrow[r];
#pragma unroll
  for (int dt = 0; dt < 4; ++dt)
#pragma unroll
    for (int r = 0; r < 4; ++r) {
      int row = qb + w * 16 + lhi * 4 + r;
      int col = h * DHEAD + dt * 16 + l15;
      o[((size_t)(b * NSEQ + row)) * INNER + col] = f2h(oacc[dt][r] * lrow[r]);
    }
}

// ---------------------------------------------------------------------------
extern "C" void kernel_launch(void* const* d_in, const int* in_sizes, int n_in,
                              void* d_out, int out_size, void* d_ws, size_t ws_size,
                              hipStream_t stream) {
  const float* x     = (const float*)d_in[0];
  const float* bias  = (const float*)d_in[1];
  const float* gamma = (const float*)d_in[2];
  const float* beta  = (const float*)d_in[3];
  const float* wq    = (const float*)d_in[4];
  const float* wkv   = (const float*)d_in[5];
  const float* wo    = (const float*)d_in[6];
  float* out = (float*)d_out;   // fp32 output (reference output dtype)

  char* ws = (char*)d_ws;
  const size_t MB = 1024 * 1024;
  short* xn    = (short*)(ws);              // 8 MB  [4096][1024]
  short* wq_t  = (short*)(ws + 8  * MB);    // 2 MB  [1024][1024]
  short* wkv_t = (short*)(ws + 10 * MB);    // 4 MB  [2048][1024]
  short* wo_t  = (short*)(ws + 14 * MB);    // 2 MB  [1024][1024]
  short* q_s   = (short*)(ws + 16 * MB);    // 8 MB  [4096][1024] (scaled)
  short* kvb   = (short*)(ws + 24 * MB);    // 16 MB [4096][2048]
  short* ao    = xn;                        // reuse xn after kv GEMM

  ln_kernel<<<MROWS, 256, 0, stream>>>(x, gamma, beta, xn);
  transpose_f16<<<dim3(INNER / 32, DIM / 32), 256, 0, stream>>>(wq, wq_t, DIM, INNER);
  transpose_f16<<<dim3(2 * INNER / 32, DIM / 32), 256, 0, stream>>>(wkv, wkv_t, DIM, 2 * INNER);
  transpose_f16<<<dim3(DIM / 32, INNER / 32), 256, 0, stream>>>(wo, wo_t, INNER, DIM);

  gemm_bt<false><<<dim3(MROWS / 128, INNER / 128), 256, 0, stream>>>(
      xn, wq_t, q_s, INNER, DIM, 0.125f);
  gemm_bt<false><<<dim3(MROWS / 128, (2 * INNER) / 128), 256, 0, stream>>>(
      xn, wkv_t, kvb, 2 * INNER, DIM, 1.0f);

  attn_kernel<<<dim3(NSEQ / 64, HEADS, NB), 256, 0, stream>>>(q_s, kvb, bias, ao);

  gemm_bt<true><<<dim3(MROWS / 128, DIM / 128), 256, 0, stream>>>(
      ao, wo_t, out, DIM, INNER, 1.0f);
}

// Round 3
// 195.079 us; speedup vs baseline: 1.2426x; 1.2426x over previous
//
#include <hip/hip_runtime.h>
#include <hip/hip_bf16.h>

#define DIM   1024
#define HEADS 16
#define DHEAD 64
#define INNER 1024
#define NSEQ  2048
#define NB    2
#define MROWS (NB * NSEQ)   // 4096

typedef __attribute__((ext_vector_type(8))) short    short8;
typedef __attribute__((ext_vector_type(4))) short    short4v;
typedef __attribute__((ext_vector_type(4))) float    floatx4;
typedef __attribute__((ext_vector_type(8))) _Float16 half8;

#define GLOBAL_AS __attribute__((address_space(1)))
#define LDS_AS    __attribute__((address_space(3)))

static __device__ __forceinline__ short f2h(float f) {
  _Float16 h = (_Float16)f;
  return __builtin_bit_cast(short, h);
}

static __device__ __forceinline__ floatx4 mfma16(short8 a, short8 b, floatx4 c) {
  return __builtin_amdgcn_mfma_f32_16x16x32_f16(
      __builtin_bit_cast(half8, a), __builtin_bit_cast(half8, b), c, 0, 0, 0);
}

// ---------------- LayerNorm: x fp32 [4096][1024] -> xn fp16 ----------------
__global__ __launch_bounds__(256) void ln_kernel(const float* __restrict__ x,
                                                 const float* __restrict__ gamma,
                                                 const float* __restrict__ beta,
                                                 short* __restrict__ xn) {
  int row = blockIdx.x;
  int t   = threadIdx.x;
  const float4* xr = reinterpret_cast<const float4*>(x + (size_t)row * DIM);
  float4 v = xr[t];
  float s  = v.x + v.y + v.z + v.w;
  float s2 = v.x * v.x + v.y * v.y + v.z * v.z + v.w * v.w;
#pragma unroll
  for (int off = 1; off < 64; off <<= 1) {
    s  += __shfl_xor(s, off);
    s2 += __shfl_xor(s2, off);
  }
  __shared__ float red[8];
  if ((t & 63) == 0) { red[t >> 6] = s; red[(t >> 6) + 4] = s2; }
  __syncthreads();
  s  = red[0] + red[1] + red[2] + red[3];
  s2 = red[4] + red[5] + red[6] + red[7];
  float mu   = s * (1.0f / DIM);
  float var  = s2 * (1.0f / DIM) - mu * mu;
  float rstd = rsqrtf(var + 1e-5f);
  float4 g  = reinterpret_cast<const float4*>(gamma)[t];
  float4 bb = reinterpret_cast<const float4*>(beta)[t];
  short4v o;
  o.x = f2h((v.x - mu) * rstd * g.x + bb.x);
  o.y = f2h((v.y - mu) * rstd * g.y + bb.y);
  o.z = f2h((v.z - mu) * rstd * g.z + bb.z);
  o.w = f2h((v.w - mu) * rstd * g.w + bb.w);
  reinterpret_cast<short4v*>(xn + (size_t)row * DIM)[t] = o;
}

// ------------- transpose + fp32->fp16: w [K][N] -> wt [N][K] ---------------
__global__ __launch_bounds__(256) void transpose_f16(const float* __restrict__ w,
                                                     short* __restrict__ wt,
                                                     int Kk, int Nn) {
  __shared__ float tile[32][33];
  int n0 = blockIdx.x * 32, k0 = blockIdx.y * 32;
  int tx = threadIdx.x & 31, ty = threadIdx.x >> 5;   // ty in [0,8)
#pragma unroll
  for (int i = 0; i < 32; i += 8)
    tile[ty + i][tx] = w[(size_t)(k0 + ty + i) * Nn + n0 + tx];
  __syncthreads();
#pragma unroll
  for (int i = 0; i < 32; i += 8)
    wt[(size_t)(n0 + ty + i) * Kk + k0 + tx] = f2h(tile[tx][ty + i]);
}

// --------- GEMM: C[M][Nn] = A[M][Kk] * Bt[Nn][Kk]^T, fp16 in ---------------
template <bool F32OUT>
__global__ __launch_bounds__(256) void gemm_bt(const short* __restrict__ A,
                                               const short* __restrict__ Bt,
                                               void* __restrict__ Cout,
                                               int Nn, int Kk, float oscale) {
  constexpr int BM = 128, BN = 128, BK = 64;
  __shared__ __attribute__((aligned(16))) short As[BM * BK];
  __shared__ __attribute__((aligned(16))) short Bs[BN * BK];
  int bm = blockIdx.x, bn = blockIdx.y;
  int t = threadIdx.x, lane = t & 63, w = t >> 6;
  int l15 = lane & 15, lhi = lane >> 4;
  int wr = w >> 1, wc = w & 1;
  floatx4 acc[4][4] = {};
  const short* Ag = A + (size_t)bm * BM * Kk;
  const short* Bg = Bt + (size_t)bn * BN * Kk;

  for (int k0 = 0; k0 < Kk; k0 += BK) {
#pragma unroll
    for (int it = 0; it < 4; ++it) {
      int base = it * 256 + w * 64;
      int idx  = base + lane;
      int row  = idx >> 3, kc = (idx & 7) << 3;
      __builtin_amdgcn_global_load_lds(
          (const GLOBAL_AS unsigned int*)(Ag + (size_t)row * Kk + k0 + kc),
          (LDS_AS unsigned int*)(As + base * 8), 16, 0, 0);
    }
#pragma unroll
    for (int it = 0; it < 4; ++it) {
      int base = it * 256 + w * 64;
      int idx  = base + lane;
      int row  = idx >> 3, kc = (idx & 7) << 3;
      __builtin_amdgcn_global_load_lds(
          (const GLOBAL_AS unsigned int*)(Bg + (size_t)row * Kk + k0 + kc),
          (LDS_AS unsigned int*)(Bs + base * 8), 16, 0, 0);
    }
    __syncthreads();
#pragma unroll
    for (int kc = 0; kc < 2; ++kc) {
      short8 a[4], b[4];
#pragma unroll
      for (int mt = 0; mt < 4; ++mt)
        a[mt] = *reinterpret_cast<const short8*>(
            &As[(wr * 64 + mt * 16 + l15) * BK + lhi * 8 + kc * 32]);
#pragma unroll
      for (int nt = 0; nt < 4; ++nt)
        b[nt] = *reinterpret_cast<const short8*>(
            &Bs[(wc * 64 + nt * 16 + l15) * BK + lhi * 8 + kc * 32]);
#pragma unroll
      for (int mt = 0; mt < 4; ++mt)
#pragma unroll
        for (int nt = 0; nt < 4; ++nt)
          acc[mt][nt] = mfma16(a[mt], b[nt], acc[mt][nt]);
    }
    __syncthreads();
  }

  int row0 = bm * BM + wr * 64;
  int col0 = bn * BN + wc * 64;
#pragma unroll
  for (int mt = 0; mt < 4; ++mt)
#pragma unroll
    for (int nt = 0; nt < 4; ++nt)
#pragma unroll
      for (int r = 0; r < 4; ++r) {
        int row = row0 + mt * 16 + lhi * 4 + r;
        int col = col0 + nt * 16 + l15;
        if (F32OUT)
          ((float*)Cout)[(size_t)row * Nn + col] = acc[mt][nt][r] * oscale;
        else
          ((short*)Cout)[(size_t)row * Nn + col] = f2h(acc[mt][nt][r] * oscale);
      }
}

// ------------------- causal flash attention, split-KV ----------------------
// grid (48, HEADS, NB), 256 threads (4 waves x 16 q-rows), pipelined staging.
// Block map (work-heavy first):
//   id in [0,16):  qt=16+id, tiles [0,16)      -> partial chunk 0
//   id in [16,32): qt=47-id, tiles [16,qt+1)   -> partial chunk 1 (diag)
//   id in [32,48): qt=47-id, tiles [0,qt+1)    -> direct write (diag)
__global__ __launch_bounds__(256) void attn_kernel(const short* __restrict__ qs,
                                                   const short* __restrict__ kvb,
                                                   const float* __restrict__ bias,
                                                   short* __restrict__ o,
                                                   float* __restrict__ Opart,
                                                   float* __restrict__ mlpart) {
  constexpr int LDK = 72;   // padded row stride (shorts)
  __shared__ __attribute__((aligned(16))) short Ks[64 * LDK];
  __shared__ __attribute__((aligned(16))) short Vt[64 * LDK];
  __shared__ __attribute__((aligned(16))) short Ps[64 * LDK];
  int id = blockIdx.x, h = blockIdx.y, b = blockIdx.z;
  int qt, tt0, tt1, pchunk;
  bool partial;
  if (id < 16)      { qt = 16 + id; tt0 = 0;  tt1 = 16;     partial = true;  pchunk = 0; }
  else if (id < 32) { qt = 47 - id; tt0 = 16; tt1 = qt + 1; partial = true;  pchunk = 1; }
  else              { qt = 47 - id; tt0 = 0;  tt1 = qt + 1; partial = false; pchunk = 0; }
  int qb = qt * 64;
  int t = threadIdx.x, lane = t & 63, w = t >> 6;
  int l15 = lane & 15, lhi = lane >> 4;

  // Q fragments: wave w owns q-rows [qb + w*16, +16)
  const short* qrow =
      qs + ((size_t)(b * NSEQ + qb + w * 16 + l15)) * INNER + h * DHEAD + lhi * 8;
  short8 qf0 = *reinterpret_cast<const short8*>(qrow);
  short8 qf1 = *reinterpret_cast<const short8*>(qrow + 32);

  const size_t kvstride = 2 * INNER;
  int krow = t >> 3, kcol = (t & 7) << 3;   // K stage: rows 0..31 (+32), 8 cols
  int rr = (t >> 3) * 2, cc = (t & 7) << 3; // V stage: row pair, 8 cols

  short8 kr0, kr1, vr0, vr1;
  floatx4 br[4];   // bias, C-fragment layout: br[jt][r]

  auto issue = [&](int tile) {
    int j0 = tile * 64;
    const short* kp =
        kvb + ((size_t)(b * NSEQ + j0 + krow)) * kvstride + h * DHEAD + kcol;
    kr0 = *reinterpret_cast<const short8*>(kp);
    kr1 = *reinterpret_cast<const short8*>(kp + 32 * kvstride);
    const short* vp = kvb + ((size_t)(b * NSEQ + j0 + rr)) * kvstride +
                      INNER + h * DHEAD + cc;
    vr0 = *reinterpret_cast<const short8*>(vp);
    vr1 = *reinterpret_cast<const short8*>(vp + kvstride);
    const float* bb =
        bias + ((size_t)h * NSEQ + (qb + w * 16 + lhi * 4)) * NSEQ + j0 + l15;
#pragma unroll
    for (int jt = 0; jt < 4; ++jt)
#pragma unroll
      for (int r = 0; r < 4; ++r)
        br[jt][r] = bb[(size_t)r * NSEQ + jt * 16];
  };

  float mrow[4], lrow[4];
  floatx4 oacc[4] = {};
#pragma unroll
  for (int r = 0; r < 4; ++r) { mrow[r] = -1e30f; lrow[r] = 0.f; }

  issue(tt0);
  for (int tt = tt0; tt < tt1; ++tt) {
    // ---- write staged K/V regs -> LDS (waits on their loads) ----
    *reinterpret_cast<short8*>(&Ks[krow * LDK + kcol]) = kr0;
    *reinterpret_cast<short8*>(&Ks[(krow + 32) * LDK + kcol]) = kr1;
#pragma unroll
    for (int e = 0; e < 8; ++e) {
      int d  = cc + e;
      int jj = rr ^ (((d >> 3) & 7) << 3);
      unsigned int pk = (unsigned short)vr0[e] |
                        ((unsigned int)(unsigned short)vr1[e] << 16);
      *reinterpret_cast<unsigned int*>(&Vt[d * LDK + jj]) = pk;
    }
    __syncthreads();

    // ---- init S with bias (frees bias regs), then prefetch next tile ----
    floatx4 s[4];
#pragma unroll
    for (int jt = 0; jt < 4; ++jt) s[jt] = br[jt];
    if (tt + 1 < tt1) issue(tt + 1);

    // ---- S += Q K^T ----
#pragma unroll
    for (int jt = 0; jt < 4; ++jt) {
      short8 kf0 = *reinterpret_cast<const short8*>(&Ks[(jt * 16 + l15) * LDK + lhi * 8]);
      short8 kf1 = *reinterpret_cast<const short8*>(&Ks[(jt * 16 + l15) * LDK + lhi * 8 + 32]);
      s[jt] = mfma16(qf0, kf0, s[jt]);
      s[jt] = mfma16(qf1, kf1, s[jt]);
    }

    // ---- causal mask (diagonal tile only) ----
    if (tt == qt) {
#pragma unroll
      for (int jt = 0; jt < 4; ++jt)
#pragma unroll
        for (int r = 0; r < 4; ++r) {
          int iloc = lhi * 4 + r;
          int jloc = jt * 16 + l15;
          if (jloc > w * 16 + iloc) s[jt][r] = -1e30f;
        }
    }

    // ---- online softmax (16-lane groups share a row set) ----
#pragma unroll
    for (int r = 0; r < 4; ++r) {
      float mx = fmaxf(fmaxf(s[0][r], s[1][r]), fmaxf(s[2][r], s[3][r]));
#pragma unroll
      for (int off = 1; off < 16; off <<= 1) mx = fmaxf(mx, __shfl_xor(mx, off));
      float mnew = fmaxf(mrow[r], mx);
      float fac  = __expf(mrow[r] - mnew);
      mrow[r] = mnew;
      float ps = 0.f;
#pragma unroll
      for (int jt = 0; jt < 4; ++jt) {
        float p = __expf(s[jt][r] - mnew);
        s[jt][r] = p;
        ps += p;
      }
#pragma unroll
      for (int off = 1; off < 16; off <<= 1) ps += __shfl_xor(ps, off);
      lrow[r] = lrow[r] * fac + ps;
#pragma unroll
      for (int dt = 0; dt < 4; ++dt) oacc[dt][r] *= fac;
    }

    // ---- P -> LDS (own-wave region; no barrier needed) ----
#pragma unroll
    for (int jt = 0; jt < 4; ++jt)
#pragma unroll
      for (int r = 0; r < 4; ++r)
        Ps[(w * 16 + lhi * 4 + r) * LDK + jt * 16 + l15] = f2h(s[jt][r]);

    // ---- O += P V ----
#pragma unroll
    for (int jc = 0; jc < 2; ++jc) {
      short8 pf = *reinterpret_cast<const short8*>(
          &Ps[(w * 16 + l15) * LDK + lhi * 8 + jc * 32]);
#pragma unroll
      for (int dt = 0; dt < 4; ++dt) {
        int dd = dt * 16 + l15;
        int jj = (lhi * 8 + jc * 32) ^ (((dd >> 3) & 7) << 3);
        short8 vf = *reinterpret_cast<const short8*>(&Vt[dd * LDK + jj]);
        oacc[dt] = mfma16(pf, vf, oacc[dt]);
      }
    }
    __syncthreads();
  }

  // ---- epilogue ----
  if (!partial) {
#pragma unroll
    for (int r = 0; r < 4; ++r) lrow[r] = 1.f / lrow[r];
#pragma unroll
    for (int dt = 0; dt < 4; ++dt)
#pragma unroll
      for (int r = 0; r < 4; ++r) {
        int row = qb + w * 16 + lhi * 4 + r;
        int col = h * DHEAD + dt * 16 + l15;
        o[((size_t)(b * NSEQ + row)) * INNER + col] = f2h(oacc[dt][r] * lrow[r]);
      }
  } else {
    size_t p = (((size_t)(b * HEADS + h) * 16 + (qt - 16)) << 1) + pchunk;
    float* Ob = Opart + p * 4096;
#pragma unroll
    for (int dt = 0; dt < 4; ++dt)
#pragma unroll
      for (int r = 0; r < 4; ++r)
        Ob[(w * 16 + lhi * 4 + r) * 64 + dt * 16 + l15] = oacc[dt][r];
    if (l15 == 0) {
#pragma unroll
      for (int r = 0; r < 4; ++r) {
        mlpart[p * 128 + (w * 16 + lhi * 4 + r)] = mrow[r];
        mlpart[p * 128 + 64 + (w * 16 + lhi * 4 + r)] = lrow[r];
      }
    }
  }
}

// ---------------- combine 2 partials per q-tile (qt >= 16) -----------------
__global__ __launch_bounds__(256) void attn_combine(const float* __restrict__ Opart,
                                                    const float* __restrict__ mlpart,
                                                    short* __restrict__ o) {
  int qi = blockIdx.x, h = blockIdx.y, b = blockIdx.z;
  int qt = 16 + qi;
  size_t p0 = ((size_t)(b * HEADS + h) * 16 + qi) << 1;
  size_t p1 = p0 + 1;
  int t = threadIdx.x;
  int row = t >> 2, cg = (t & 3) << 4;
  float m0 = mlpart[p0 * 128 + row], l0 = mlpart[p0 * 128 + 64 + row];
  float m1 = mlpart[p1 * 128 + row], l1 = mlpart[p1 * 128 + 64 + row];
  float M  = fmaxf(m0, m1);
  float w0 = __expf(m0 - M), w1 = __expf(m1 - M);
  float inv = 1.f / (w0 * l0 + w1 * l1);
  const float4* O0 = reinterpret_cast<const float4*>(Opart + p0 * 4096 + row * 64 + cg);
  const float4* O1 = reinterpret_cast<const float4*>(Opart + p1 * 4096 + row * 64 + cg);
  short* op = o + ((size_t)(b * NSEQ + qt * 64 + row)) * INNER + h * DHEAD + cg;
#pragma unroll
  for (int i = 0; i < 4; ++i) {
    float4 a = O0[i], c = O1[i];
    short4v ov;
    ov.x = f2h((w0 * a.x + w1 * c.x) * inv);
    ov.y = f2h((w0 * a.y + w1 * c.y) * inv);
    ov.z = f2h((w0 * a.z + w1 * c.z) * inv);
    ov.w = f2h((w0 * a.w + w1 * c.w) * inv);
    reinterpret_cast<short4v*>(op)[i] = ov;
  }
}

// ---------------------------------------------------------------------------
extern "C" void kernel_launch(void* const* d_in, const int* in_sizes, int n_in,
                              void* d_out, int out_size, void* d_ws, size_t ws_size,
                              hipStream_t stream) {
  const float* x     = (const float*)d_in[0];
  const float* bias  = (const float*)d_in[1];
  const float* gamma = (const float*)d_in[2];
  const float* beta  = (const float*)d_in[3];
  const float* wq    = (const float*)d_in[4];
  const float* wkv   = (const float*)d_in[5];
  const float* wo    = (const float*)d_in[6];
  float* out = (float*)d_out;   // fp32 output

  char* ws = (char*)d_ws;
  const size_t MB = 1024 * 1024;
  short* xn     = (short*)(ws);              // 8 MB  [4096][1024]
  short* wq_t   = (short*)(ws + 8  * MB);    // 2 MB
  short* wkv_t  = (short*)(ws + 10 * MB);    // 4 MB
  short* wo_t   = (short*)(ws + 14 * MB);    // 2 MB
  short* q_s    = (short*)(ws + 16 * MB);    // 8 MB (scaled q)
  short* kvb    = (short*)(ws + 24 * MB);    // 16 MB [4096][2048]
  float* Opart  = (float*)(ws + 40 * MB);    // 16 MB [1024][64][64]
  float* mlpart = (float*)(ws + 56 * MB);    // 0.5 MB [1024][128]
  short* ao     = xn;                        // reuse xn after kv GEMM

  ln_kernel<<<MROWS, 256, 0, stream>>>(x, gamma, beta, xn);
  transpose_f16<<<dim3(INNER / 32, DIM / 32), 256, 0, stream>>>(wq, wq_t, DIM, INNER);
  transpose_f16<<<dim3(2 * INNER / 32, DIM / 32), 256, 0, stream>>>(wkv, wkv_t, DIM, 2 * INNER);
  transpose_f16<<<dim3(DIM / 32, INNER / 32), 256, 0, stream>>>(wo, wo_t, INNER, DIM);

  gemm_bt<false><<<dim3(MROWS / 128, INNER / 128), 256, 0, stream>>>(
      xn, wq_t, q_s, INNER, DIM, 0.125f);
  gemm_bt<false><<<dim3(MROWS / 128, (2 * INNER) / 128), 256, 0, stream>>>(
      xn, wkv_t, kvb, 2 * INNER, DIM, 1.0f);

  attn_kernel<<<dim3(48, HEADS, NB), 256, 0, stream>>>(q_s, kvb, bias, ao,
                                                       Opart, mlpart);
  attn_combine<<<dim3(16, HEADS, NB), 256, 0, stream>>>(Opart, mlpart, ao);

  gemm_bt<true><<<dim3(MROWS / 128, DIM / 128), 256, 0, stream>>>(
      ao, wo_t, out, DIM, INNER, 1.0f);
}

// Round 4
// 182.508 us; speedup vs baseline: 1.3282x; 1.0689x over previous
//
#include <hip/hip_runtime.h>
#include <hip/hip_bf16.h>

#define DIM   1024
#define HEADS 16
#define DHEAD 64
#define INNER 1024
#define NSEQ  2048
#define NB    2
#define MROWS (NB * NSEQ)   // 4096
#define QS    (3 * INNER)   // fused qkv row stride

typedef __attribute__((ext_vector_type(8))) short    short8;
typedef __attribute__((ext_vector_type(4))) short    short4v;
typedef __attribute__((ext_vector_type(4))) float    floatx4;
typedef __attribute__((ext_vector_type(8))) _Float16 half8;

#define GLOBAL_AS __attribute__((address_space(1)))
#define LDS_AS    __attribute__((address_space(3)))

static __device__ __forceinline__ short f2h(float f) {
  _Float16 h = (_Float16)f;
  return __builtin_bit_cast(short, h);
}
static __device__ __forceinline__ float h2f(short s) {
  return (float)__builtin_bit_cast(_Float16, s);
}

static __device__ __forceinline__ floatx4 mfma16(short8 a, short8 b, floatx4 c) {
  return __builtin_amdgcn_mfma_f32_16x16x32_f16(
      __builtin_bit_cast(half8, a), __builtin_bit_cast(half8, b), c, 0, 0, 0);
}

// ---------------- LayerNorm: x fp32 [4096][1024] -> xn fp16 ----------------
__global__ __launch_bounds__(256) void ln_kernel(const float* __restrict__ x,
                                                 const float* __restrict__ gamma,
                                                 const float* __restrict__ beta,
                                                 short* __restrict__ xn) {
  int row = blockIdx.x;
  int t   = threadIdx.x;
  const float4* xr = reinterpret_cast<const float4*>(x + (size_t)row * DIM);
  float4 v = xr[t];
  float s  = v.x + v.y + v.z + v.w;
  float s2 = v.x * v.x + v.y * v.y + v.z * v.z + v.w * v.w;
#pragma unroll
  for (int off = 1; off < 64; off <<= 1) {
    s  += __shfl_xor(s, off);
    s2 += __shfl_xor(s2, off);
  }
  __shared__ float red[8];
  if ((t & 63) == 0) { red[t >> 6] = s; red[(t >> 6) + 4] = s2; }
  __syncthreads();
  s  = red[0] + red[1] + red[2] + red[3];
  s2 = red[4] + red[5] + red[6] + red[7];
  float mu   = s * (1.0f / DIM);
  float var  = s2 * (1.0f / DIM) - mu * mu;
  float rstd = rsqrtf(var + 1e-5f);
  float4 g  = reinterpret_cast<const float4*>(gamma)[t];
  float4 bb = reinterpret_cast<const float4*>(beta)[t];
  short4v o;
  o.x = f2h((v.x - mu) * rstd * g.x + bb.x);
  o.y = f2h((v.y - mu) * rstd * g.y + bb.y);
  o.z = f2h((v.z - mu) * rstd * g.z + bb.z);
  o.w = f2h((v.w - mu) * rstd * g.w + bb.w);
  reinterpret_cast<short4v*>(xn + (size_t)row * DIM)[t] = o;
}

// ------------- transpose + fp32->fp16: w [K][N] -> wt [N][K] ---------------
__global__ __launch_bounds__(256) void transpose_f16(const float* __restrict__ w,
                                                     short* __restrict__ wt,
                                                     int Kk, int Nn) {
  __shared__ float tile[32][33];
  int n0 = blockIdx.x * 32, k0 = blockIdx.y * 32;
  int tx = threadIdx.x & 31, ty = threadIdx.x >> 5;   // ty in [0,8)
#pragma unroll
  for (int i = 0; i < 32; i += 8)
    tile[ty + i][tx] = w[(size_t)(k0 + ty + i) * Nn + n0 + tx];
  __syncthreads();
#pragma unroll
  for (int i = 0; i < 32; i += 8)
    wt[(size_t)(n0 + ty + i) * Kk + k0 + tx] = f2h(tile[tx][ty + i]);
}

// --------- GEMM: C[M][Nn] = A[M][Kk] * Bt[Nn][Kk]^T, fp16 in ---------------
// oscale applies to output cols < qsplit, oscale2 to the rest (block-uniform).
template <bool F32OUT>
__global__ __launch_bounds__(256) void gemm_bt(const short* __restrict__ A,
                                               const short* __restrict__ Bt,
                                               void* __restrict__ Cout,
                                               int Nn, int Kk,
                                               float oscale, float oscale2,
                                               int qsplit) {
  constexpr int BM = 128, BN = 128, BK = 64;
  __shared__ __attribute__((aligned(16))) short As[BM * BK];
  __shared__ __attribute__((aligned(16))) short Bs[BN * BK];
  int bm = blockIdx.x, bn = blockIdx.y;
  int t = threadIdx.x, lane = t & 63, w = t >> 6;
  int l15 = lane & 15, lhi = lane >> 4;
  int wr = w >> 1, wc = w & 1;
  float osc = (bn * BN < qsplit) ? oscale : oscale2;
  floatx4 acc[4][4] = {};
  const short* Ag = A + (size_t)bm * BM * Kk;
  const short* Bg = Bt + (size_t)bn * BN * Kk;

  for (int k0 = 0; k0 < Kk; k0 += BK) {
#pragma unroll
    for (int it = 0; it < 4; ++it) {
      int base = it * 256 + w * 64;
      int idx  = base + lane;
      int row  = idx >> 3, kc = (idx & 7) << 3;
      __builtin_amdgcn_global_load_lds(
          (const GLOBAL_AS unsigned int*)(Ag + (size_t)row * Kk + k0 + kc),
          (LDS_AS unsigned int*)(As + base * 8), 16, 0, 0);
    }
#pragma unroll
    for (int it = 0; it < 4; ++it) {
      int base = it * 256 + w * 64;
      int idx  = base + lane;
      int row  = idx >> 3, kc = (idx & 7) << 3;
      __builtin_amdgcn_global_load_lds(
          (const GLOBAL_AS unsigned int*)(Bg + (size_t)row * Kk + k0 + kc),
          (LDS_AS unsigned int*)(Bs + base * 8), 16, 0, 0);
    }
    __syncthreads();
#pragma unroll
    for (int kc = 0; kc < 2; ++kc) {
      short8 a[4], b[4];
#pragma unroll
      for (int mt = 0; mt < 4; ++mt)
        a[mt] = *reinterpret_cast<const short8*>(
            &As[(wr * 64 + mt * 16 + l15) * BK + lhi * 8 + kc * 32]);
#pragma unroll
      for (int nt = 0; nt < 4; ++nt)
        b[nt] = *reinterpret_cast<const short8*>(
            &Bs[(wc * 64 + nt * 16 + l15) * BK + lhi * 8 + kc * 32]);
#pragma unroll
      for (int mt = 0; mt < 4; ++mt)
#pragma unroll
        for (int nt = 0; nt < 4; ++nt)
          acc[mt][nt] = mfma16(a[mt], b[nt], acc[mt][nt]);
    }
    __syncthreads();
  }

  int row0 = bm * BM + wr * 64;
  int col0 = bn * BN + wc * 64;
#pragma unroll
  for (int mt = 0; mt < 4; ++mt)
#pragma unroll
    for (int nt = 0; nt < 4; ++nt)
#pragma unroll
      for (int r = 0; r < 4; ++r) {
        int row = row0 + mt * 16 + lhi * 4 + r;
        int col = col0 + nt * 16 + l15;
        if (F32OUT)
          ((float*)Cout)[(size_t)row * Nn + col] = acc[mt][nt][r] * osc;
        else
          ((short*)Cout)[(size_t)row * Nn + col] = f2h(acc[mt][nt][r] * osc);
      }
}

// ------------- causal flash attention, uniform 8-tile chunks ---------------
// grid (80, HEADS, NB), 256 threads (4 waves x 16 q-rows).
// id -> (qt, chunk): c0: qt=31-id (32), c1: qt=63-id (24), c2: 87-id (16),
// c3: 103-id (8). Chunk c covers KV tiles [8c, min(8c+8, qt+1)).
// All chunks write fp16 unnormalized partial O + fp32 (m,l).
__global__ __launch_bounds__(256) void attn_kernel(const short* __restrict__ qkv,
                                                   const float* __restrict__ bias,
                                                   short* __restrict__ Opart,
                                                   float* __restrict__ mlpart) {
  constexpr int LDK = 72;   // padded row stride (shorts)
  __shared__ __attribute__((aligned(16))) short Ks[2][64 * LDK];
  __shared__ __attribute__((aligned(16))) short Vt[2][64 * LDK];
  __shared__ __attribute__((aligned(16))) short Ps[64 * LDK];
  int id = blockIdx.x, h = blockIdx.y, b = blockIdx.z;
  int qt, c;
  if (id < 32)      { c = 0; qt = 31 - id; }
  else if (id < 56) { c = 1; qt = 63 - id; }
  else if (id < 72) { c = 2; qt = 87 - id; }
  else              { c = 3; qt = 103 - id; }
  int tt0 = c * 8;
  int tt1 = (tt0 + 8 < qt + 1) ? (tt0 + 8) : (qt + 1);
  int qb = qt * 64;
  int t = threadIdx.x, lane = t & 63, w = t >> 6;
  int l15 = lane & 15, lhi = lane >> 4;

  // Q fragments: wave w owns q-rows [qb + w*16, +16); q pre-scaled by 0.125
  const short* qrow =
      qkv + ((size_t)(b * NSEQ + qb + w * 16 + l15)) * QS + h * DHEAD + lhi * 8;
  short8 qf0 = *reinterpret_cast<const short8*>(qrow);
  short8 qf1 = *reinterpret_cast<const short8*>(qrow + 32);

  int krow = t >> 3, kcol = (t & 7) << 3;   // K stage: rows 0..31 (+32)
  int rr = (t >> 3) * 2, cc = (t & 7) << 3; // V stage: row pair, 8 cols
  short8 kr0, kr1, vr0, vr1;

  auto issue_kv = [&](int tile) {
    int j0 = tile * 64;
    const short* kp =
        qkv + ((size_t)(b * NSEQ + j0 + krow)) * QS + INNER + h * DHEAD + kcol;
    kr0 = *reinterpret_cast<const short8*>(kp);
    kr1 = *reinterpret_cast<const short8*>(kp + (size_t)32 * QS);
    const short* vp = qkv + ((size_t)(b * NSEQ + j0 + rr)) * QS +
                      2 * INNER + h * DHEAD + cc;
    vr0 = *reinterpret_cast<const short8*>(vp);
    vr1 = *reinterpret_cast<const short8*>(vp + QS);
  };
  auto issue_bias = [&](int tile, floatx4 (&br)[4]) {
    const float* bb =
        bias + ((size_t)h * NSEQ + (qb + w * 16 + lhi * 4)) * NSEQ + tile * 64 + l15;
#pragma unroll
    for (int jt = 0; jt < 4; ++jt)
#pragma unroll
      for (int r = 0; r < 4; ++r)
        br[jt][r] = bb[(size_t)r * NSEQ + jt * 16];
  };
  auto writeKV = [&](int buf) {
    *reinterpret_cast<short8*>(&Ks[buf][krow * LDK + kcol]) = kr0;
    *reinterpret_cast<short8*>(&Ks[buf][(krow + 32) * LDK + kcol]) = kr1;
#pragma unroll
    for (int e = 0; e < 8; ++e) {
      int d  = cc + e;
      int jj = rr ^ (((d >> 3) & 7) << 3);
      unsigned int pk = (unsigned short)vr0[e] |
                        ((unsigned int)(unsigned short)vr1[e] << 16);
      *reinterpret_cast<unsigned int*>(&Vt[buf][d * LDK + jj]) = pk;
    }
  };

  float mrow[4], lrow[4];
  floatx4 oacc[4] = {};
#pragma unroll
  for (int r = 0; r < 4; ++r) { mrow[r] = -1e30f; lrow[r] = 0.f; }

  auto step = [&](int tt, int buf, floatx4 (&br)[4]) {
    if (tt + 1 < tt1) issue_kv(tt + 1);
    __syncthreads();   // buf published by previous step's writeKV

    floatx4 s[4];
#pragma unroll
    for (int jt = 0; jt < 4; ++jt) s[jt] = br[jt];   // waits bias loads
    if (tt + 2 < tt1) issue_bias(tt + 2, br);        // distance-2 prefetch

#pragma unroll
    for (int jt = 0; jt < 4; ++jt) {
      short8 kf0 = *reinterpret_cast<const short8*>(
          &Ks[buf][(jt * 16 + l15) * LDK + lhi * 8]);
      short8 kf1 = *reinterpret_cast<const short8*>(
          &Ks[buf][(jt * 16 + l15) * LDK + lhi * 8 + 32]);
      s[jt] = mfma16(qf0, kf0, s[jt]);
      s[jt] = mfma16(qf1, kf1, s[jt]);
    }

    if (tt == qt) {   // diagonal tile: causal mask
#pragma unroll
      for (int jt = 0; jt < 4; ++jt)
#pragma unroll
        for (int r = 0; r < 4; ++r) {
          int iloc = lhi * 4 + r;
          int jloc = jt * 16 + l15;
          if (jloc > w * 16 + iloc) s[jt][r] = -1e30f;
        }
    }

#pragma unroll
    for (int r = 0; r < 4; ++r) {
      float mx = fmaxf(fmaxf(s[0][r], s[1][r]), fmaxf(s[2][r], s[3][r]));
#pragma unroll
      for (int off = 1; off < 16; off <<= 1) mx = fmaxf(mx, __shfl_xor(mx, off));
      float mnew = fmaxf(mrow[r], mx);
      float fac  = __expf(mrow[r] - mnew);
      mrow[r] = mnew;
      float ps = 0.f;
#pragma unroll
      for (int jt = 0; jt < 4; ++jt) {
        float p = __expf(s[jt][r] - mnew);
        s[jt][r] = p;
        ps += p;
      }
#pragma unroll
      for (int off = 1; off < 16; off <<= 1) ps += __shfl_xor(ps, off);
      lrow[r] = lrow[r] * fac + ps;
#pragma unroll
      for (int dt = 0; dt < 4; ++dt) oacc[dt][r] *= fac;
    }

    // P -> LDS (wave-private rows; within-wave ordering only)
#pragma unroll
    for (int jt = 0; jt < 4; ++jt)
#pragma unroll
      for (int r = 0; r < 4; ++r)
        Ps[(w * 16 + lhi * 4 + r) * LDK + jt * 16 + l15] = f2h(s[jt][r]);

#pragma unroll
    for (int jc = 0; jc < 2; ++jc) {
      short8 pf = *reinterpret_cast<const short8*>(
          &Ps[(w * 16 + l15) * LDK + lhi * 8 + jc * 32]);
#pragma unroll
      for (int dt = 0; dt < 4; ++dt) {
        int dd = dt * 16 + l15;
        int jj = (lhi * 8 + jc * 32) ^ (((dd >> 3) & 7) << 3);
        short8 vf = *reinterpret_cast<const short8*>(&Vt[buf][dd * LDK + jj]);
        oacc[dt] = mfma16(pf, vf, oacc[dt]);
      }
    }

    if (tt + 1 < tt1) writeKV(buf ^ 1);   // safe: nobody reads buf^1 this step
  };

  floatx4 brA[4], brB[4];
  issue_kv(tt0);
  issue_bias(tt0, brA);
  if (tt0 + 1 < tt1) issue_bias(tt0 + 1, brB);
  writeKV(0);

  int nt = tt1 - tt0;
  for (int i = 0; i < nt; i += 2) {
    step(tt0 + i, 0, brA);
    if (i + 1 < nt) step(tt0 + i + 1, 1, brB);
  }

  // ---- partial epilogue (fp16 O, fp32 m/l) ----
  size_t p = (size_t)(b * HEADS + h) * 80 + id;
  short* Ob = Opart + p * 4096;
#pragma unroll
  for (int dt = 0; dt < 4; ++dt)
#pragma unroll
    for (int r = 0; r < 4; ++r)
      Ob[(w * 16 + lhi * 4 + r) * 64 + dt * 16 + l15] = f2h(oacc[dt][r]);
  if (l15 == 0) {
#pragma unroll
    for (int r = 0; r < 4; ++r) {
      mlpart[p * 128 + (w * 16 + lhi * 4 + r)] = mrow[r];
      mlpart[p * 128 + 64 + (w * 16 + lhi * 4 + r)] = lrow[r];
    }
  }
}

// ---------------- combine 1..4 partials per q-tile -------------------------
__global__ __launch_bounds__(256) void attn_combine(const short* __restrict__ Opart,
                                                    const float* __restrict__ mlpart,
                                                    short* __restrict__ o) {
  int qt = blockIdx.x, h = blockIdx.y, b = blockIdx.z;
  int nc = qt / 8 + 1;
  int t = threadIdx.x, row = t >> 2, cg = (t & 3) << 4;
  size_t base = (size_t)(b * HEADS + h) * 80;
  const int idtab[4] = {31, 63, 87, 103};

  float M = -1e30f;
  float mv0 = 0, mv1 = 0, mv2 = 0, mv3 = 0, lv0 = 0, lv1 = 0, lv2 = 0, lv3 = 0;
  {
    size_t p = base + idtab[0] - qt;
    mv0 = mlpart[p * 128 + row]; lv0 = mlpart[p * 128 + 64 + row];
    M = mv0;
  }
  if (nc > 1) { size_t p = base + idtab[1] - qt;
    mv1 = mlpart[p * 128 + row]; lv1 = mlpart[p * 128 + 64 + row]; M = fmaxf(M, mv1); }
  if (nc > 2) { size_t p = base + idtab[2] - qt;
    mv2 = mlpart[p * 128 + row]; lv2 = mlpart[p * 128 + 64 + row]; M = fmaxf(M, mv2); }
  if (nc > 3) { size_t p = base + idtab[3] - qt;
    mv3 = mlpart[p * 128 + row]; lv3 = mlpart[p * 128 + 64 + row]; M = fmaxf(M, mv3); }

  float acc[16] = {};
  float lsum = 0.f;
#pragma unroll
  for (int c2 = 0; c2 < 4; ++c2) {
    if (c2 >= nc) break;
    float mc = (c2 == 0) ? mv0 : (c2 == 1) ? mv1 : (c2 == 2) ? mv2 : mv3;
    float lc = (c2 == 0) ? lv0 : (c2 == 1) ? lv1 : (c2 == 2) ? lv2 : lv3;
    float wgt = __expf(mc - M);
    lsum += wgt * lc;
    size_t p = base + idtab[c2] - qt;
    const short8* Or =
        reinterpret_cast<const short8*>(Opart + p * 4096 + row * 64 + cg);
    short8 a0 = Or[0], a1 = Or[1];
#pragma unroll
    for (int e = 0; e < 8; ++e) {
      acc[e]     += wgt * h2f(a0[e]);
      acc[8 + e] += wgt * h2f(a1[e]);
    }
  }
  float inv = 1.f / lsum;
  short* op = o + ((size_t)(b * NSEQ + qt * 64 + row)) * INNER + h * DHEAD + cg;
  short8 o0, o1;
#pragma unroll
  for (int e = 0; e < 8; ++e) {
    o0[e] = f2h(acc[e] * inv);
    o1[e] = f2h(acc[8 + e] * inv);
  }
  reinterpret_cast<short8*>(op)[0] = o0;
  reinterpret_cast<short8*>(op)[1] = o1;
}

// ---------------------------------------------------------------------------
extern "C" void kernel_launch(void* const* d_in, const int* in_sizes, int n_in,
                              void* d_out, int out_size, void* d_ws, size_t ws_size,
                              hipStream_t stream) {
  const float* x     = (const float*)d_in[0];
  const float* bias  = (const float*)d_in[1];
  const float* gamma = (const float*)d_in[2];
  const float* beta  = (const float*)d_in[3];
  const float* wq    = (const float*)d_in[4];
  const float* wkv   = (const float*)d_in[5];
  const float* wo    = (const float*)d_in[6];
  float* out = (float*)d_out;   // fp32 output

  char* ws = (char*)d_ws;
  const size_t MB = 1024 * 1024;
  short* xn      = (short*)(ws);              // 8 MB  [4096][1024]
  short* wqkv_t  = (short*)(ws + 8  * MB);    // 6 MB  [3072][1024]
  short* wo_t    = (short*)(ws + 14 * MB);    // 2 MB  [1024][1024]
  short* qkv     = (short*)(ws + 16 * MB);    // 24 MB [4096][3072]
  short* Opart   = (short*)(ws + 40 * MB);    // 20 MB [2560][64][64] fp16
  float* mlpart  = (float*)(ws + 60 * MB);    // 1.25 MB [2560][128]
  short* ao      = xn;                        // reuse xn after qkv GEMM

  ln_kernel<<<MROWS, 256, 0, stream>>>(x, gamma, beta, xn);
  transpose_f16<<<dim3(INNER / 32, DIM / 32), 256, 0, stream>>>(wq, wqkv_t, DIM, INNER);
  transpose_f16<<<dim3(2 * INNER / 32, DIM / 32), 256, 0, stream>>>(
      wkv, wqkv_t + (size_t)1024 * 1024, DIM, 2 * INNER);
  transpose_f16<<<dim3(DIM / 32, INNER / 32), 256, 0, stream>>>(wo, wo_t, INNER, DIM);

  // fused q|kv projection: cols < 1024 get the q scale 0.125
  gemm_bt<false><<<dim3(MROWS / 128, QS / 128), 256, 0, stream>>>(
      xn, wqkv_t, qkv, QS, DIM, 0.125f, 1.0f, 1024);

  attn_kernel<<<dim3(80, HEADS, NB), 256, 0, stream>>>(qkv, bias, Opart, mlpart);
  attn_combine<<<dim3(32, HEADS, NB), 256, 0, stream>>>(Opart, mlpart, ao);

  gemm_bt<true><<<dim3(MROWS / 128, DIM / 128), 256, 0, stream>>>(
      ao, wo_t, out, DIM, INNER, 1.0f, 1.0f, 0);
}

// Round 5
// 174.999 us; speedup vs baseline: 1.3852x; 1.0429x over previous
//
#include <hip/hip_runtime.h>
#include <hip/hip_bf16.h>

#define DIM   1024
#define HEADS 16
#define DHEAD 64
#define INNER 1024
#define NSEQ  2048
#define NB    2
#define MROWS (NB * NSEQ)   // 4096
#define QS    (3 * INNER)   // fused qkv row stride

typedef __attribute__((ext_vector_type(8))) short    short8;
typedef __attribute__((ext_vector_type(4))) short    short4v;
typedef __attribute__((ext_vector_type(4))) float    floatx4;
typedef __attribute__((ext_vector_type(8))) _Float16 half8;

#define GLOBAL_AS __attribute__((address_space(1)))
#define LDS_AS    __attribute__((address_space(3)))

static __device__ __forceinline__ short f2h(float f) {
  _Float16 h = (_Float16)f;
  return __builtin_bit_cast(short, h);
}
static __device__ __forceinline__ float h2f(short s) {
  return (float)__builtin_bit_cast(_Float16, s);
}

static __device__ __forceinline__ floatx4 mfma16(short8 a, short8 b, floatx4 c) {
  return __builtin_amdgcn_mfma_f32_16x16x32_f16(
      __builtin_bit_cast(half8, a), __builtin_bit_cast(half8, b), c, 0, 0, 0);
}

// ---------------- LayerNorm: x fp32 [4096][1024] -> xn fp16 ----------------
__global__ __launch_bounds__(256) void ln_kernel(const float* __restrict__ x,
                                                 const float* __restrict__ gamma,
                                                 const float* __restrict__ beta,
                                                 short* __restrict__ xn) {
  int row = blockIdx.x;
  int t   = threadIdx.x;
  const float4* xr = reinterpret_cast<const float4*>(x + (size_t)row * DIM);
  float4 v = xr[t];
  float s  = v.x + v.y + v.z + v.w;
  float s2 = v.x * v.x + v.y * v.y + v.z * v.z + v.w * v.w;
#pragma unroll
  for (int off = 1; off < 64; off <<= 1) {
    s  += __shfl_xor(s, off);
    s2 += __shfl_xor(s2, off);
  }
  __shared__ float red[8];
  if ((t & 63) == 0) { red[t >> 6] = s; red[(t >> 6) + 4] = s2; }
  __syncthreads();
  s  = red[0] + red[1] + red[2] + red[3];
  s2 = red[4] + red[5] + red[6] + red[7];
  float mu   = s * (1.0f / DIM);
  float var  = s2 * (1.0f / DIM) - mu * mu;
  float rstd = rsqrtf(var + 1e-5f);
  float4 g  = reinterpret_cast<const float4*>(gamma)[t];
  float4 bb = reinterpret_cast<const float4*>(beta)[t];
  short4v o;
  o.x = f2h((v.x - mu) * rstd * g.x + bb.x);
  o.y = f2h((v.y - mu) * rstd * g.y + bb.y);
  o.z = f2h((v.z - mu) * rstd * g.z + bb.z);
  o.w = f2h((v.w - mu) * rstd * g.w + bb.w);
  reinterpret_cast<short4v*>(xn + (size_t)row * DIM)[t] = o;
}

// ------------- transpose + fp32->fp16: w [K][N] -> wt [N][K] ---------------
__global__ __launch_bounds__(256) void transpose_f16(const float* __restrict__ w,
                                                     short* __restrict__ wt,
                                                     int Kk, int Nn) {
  __shared__ float tile[32][33];
  int n0 = blockIdx.x * 32, k0 = blockIdx.y * 32;
  int tx = threadIdx.x & 31, ty = threadIdx.x >> 5;   // ty in [0,8)
#pragma unroll
  for (int i = 0; i < 32; i += 8)
    tile[ty + i][tx] = w[(size_t)(k0 + ty + i) * Nn + n0 + tx];
  __syncthreads();
#pragma unroll
  for (int i = 0; i < 32; i += 8)
    wt[(size_t)(n0 + ty + i) * Kk + k0 + tx] = f2h(tile[tx][ty + i]);
}

// --------- GEMM: C[M][Nn] = A[M][Kk] * Bt[Nn][Kk]^T, fp16 in ---------------
// oscale applies to output cols < qsplit, oscale2 to the rest (block-uniform).
template <bool F32OUT>
__global__ __launch_bounds__(256) void gemm_bt(const short* __restrict__ A,
                                               const short* __restrict__ Bt,
                                               void* __restrict__ Cout,
                                               int Nn, int Kk,
                                               float oscale, float oscale2,
                                               int qsplit) {
  constexpr int BM = 128, BN = 128, BK = 64;
  __shared__ __attribute__((aligned(16))) short As[BM * BK];
  __shared__ __attribute__((aligned(16))) short Bs[BN * BK];
  int bm = blockIdx.x, bn = blockIdx.y;
  int t = threadIdx.x, lane = t & 63, w = t >> 6;
  int l15 = lane & 15, lhi = lane >> 4;
  int wr = w >> 1, wc = w & 1;
  float osc = (bn * BN < qsplit) ? oscale : oscale2;
  floatx4 acc[4][4] = {};
  const short* Ag = A + (size_t)bm * BM * Kk;
  const short* Bg = Bt + (size_t)bn * BN * Kk;

  for (int k0 = 0; k0 < Kk; k0 += BK) {
#pragma unroll
    for (int it = 0; it < 4; ++it) {
      int base = it * 256 + w * 64;
      int idx  = base + lane;
      int row  = idx >> 3, kc = (idx & 7) << 3;
      __builtin_amdgcn_global_load_lds(
          (const GLOBAL_AS unsigned int*)(Ag + (size_t)row * Kk + k0 + kc),
          (LDS_AS unsigned int*)(As + base * 8), 16, 0, 0);
    }
#pragma unroll
    for (int it = 0; it < 4; ++it) {
      int base = it * 256 + w * 64;
      int idx  = base + lane;
      int row  = idx >> 3, kc = (idx & 7) << 3;
      __builtin_amdgcn_global_load_lds(
          (const GLOBAL_AS unsigned int*)(Bg + (size_t)row * Kk + k0 + kc),
          (LDS_AS unsigned int*)(Bs + base * 8), 16, 0, 0);
    }
    __syncthreads();
#pragma unroll
    for (int kc = 0; kc < 2; ++kc) {
      short8 a[4], b[4];
#pragma unroll
      for (int mt = 0; mt < 4; ++mt)
        a[mt] = *reinterpret_cast<const short8*>(
            &As[(wr * 64 + mt * 16 + l15) * BK + lhi * 8 + kc * 32]);
#pragma unroll
      for (int nt = 0; nt < 4; ++nt)
        b[nt] = *reinterpret_cast<const short8*>(
            &Bs[(wc * 64 + nt * 16 + l15) * BK + lhi * 8 + kc * 32]);
#pragma unroll
      for (int mt = 0; mt < 4; ++mt)
#pragma unroll
        for (int nt = 0; nt < 4; ++nt)
          acc[mt][nt] = mfma16(a[mt], b[nt], acc[mt][nt]);
    }
    __syncthreads();
  }

  int row0 = bm * BM + wr * 64;
  int col0 = bn * BN + wc * 64;
#pragma unroll
  for (int mt = 0; mt < 4; ++mt)
#pragma unroll
    for (int nt = 0; nt < 4; ++nt)
#pragma unroll
      for (int r = 0; r < 4; ++r) {
        int row = row0 + mt * 16 + lhi * 4 + r;
        int col = col0 + nt * 16 + l15;
        if (F32OUT)
          ((float*)Cout)[(size_t)row * Nn + col] = acc[mt][nt][r] * osc;
        else
          ((short*)Cout)[(size_t)row * Nn + col] = f2h(acc[mt][nt][r] * osc);
      }
}

// ------------- causal flash attention, uniform 8-tile chunks ---------------
// grid (80, HEADS, NB), 256 threads (4 waves x 16 q-rows).
// SWAPPED QK^T: s = mfma(K, Q) so S frag = [kv=jt*16+lhi*4+r][q=l15] —
// each lane owns one q-row; softmax reduce = local + 2 shfl_xor.
__global__ __launch_bounds__(256) void attn_kernel(const short* __restrict__ qkv,
                                                   const float* __restrict__ bias,
                                                   short* __restrict__ Opart,
                                                   float* __restrict__ mlpart) {
  constexpr int LDK = 72;   // padded row stride (shorts)
  __shared__ __attribute__((aligned(16))) short Ks[2][64 * LDK];
  __shared__ __attribute__((aligned(16))) short Vt[2][64 * LDK];
  __shared__ __attribute__((aligned(16))) short Ps[64 * LDK];
  int id = blockIdx.x, h = blockIdx.y, b = blockIdx.z;
  int qt, c;
  if (id < 32)      { c = 0; qt = 31 - id; }
  else if (id < 56) { c = 1; qt = 63 - id; }
  else if (id < 72) { c = 2; qt = 87 - id; }
  else              { c = 3; qt = 103 - id; }
  int tt0 = c * 8;
  int tt1 = (tt0 + 8 < qt + 1) ? (tt0 + 8) : (qt + 1);
  int qb = qt * 64;
  int t = threadIdx.x, lane = t & 63, w = t >> 6;
  int l15 = lane & 15, lhi = lane >> 4;

  // Q fragments (B-operand): lane holds Q[q=l15][d=lhi*8+e]; q pre-scaled.
  const short* qrow =
      qkv + ((size_t)(b * NSEQ + qb + w * 16 + l15)) * QS + h * DHEAD + lhi * 8;
  short8 qf0 = *reinterpret_cast<const short8*>(qrow);
  short8 qf1 = *reinterpret_cast<const short8*>(qrow + 32);

  int krow = t >> 3, kcol = (t & 7) << 3;   // K stage: rows 0..31 (+32)
  int rr = (t >> 3) * 2, cc = (t & 7) << 3; // V stage: row pair, 8 cols
  short8 kr0, kr1, vr0, vr1;

  auto issue_kv = [&](int tile) {
    int j0 = tile * 64;
    const short* kp =
        qkv + ((size_t)(b * NSEQ + j0 + krow)) * QS + INNER + h * DHEAD + kcol;
    kr0 = *reinterpret_cast<const short8*>(kp);
    kr1 = *reinterpret_cast<const short8*>(kp + (size_t)32 * QS);
    const short* vp = qkv + ((size_t)(b * NSEQ + j0 + rr)) * QS +
                      2 * INNER + h * DHEAD + cc;
    vr0 = *reinterpret_cast<const short8*>(vp);
    vr1 = *reinterpret_cast<const short8*>(vp + QS);
  };
  // bias in swapped C-frag layout: br[jt][r] = bias[q=l15][kv=jt*16+lhi*4+r]
  auto issue_bias = [&](int tile, floatx4 (&br)[4]) {
    const float* bb =
        bias + ((size_t)h * NSEQ + (qb + w * 16 + l15)) * NSEQ + tile * 64 + lhi * 4;
#pragma unroll
    for (int jt = 0; jt < 4; ++jt)
      br[jt] = *reinterpret_cast<const floatx4*>(bb + jt * 16);
  };
  auto writeKV = [&](int buf) {
    *reinterpret_cast<short8*>(&Ks[buf][krow * LDK + kcol]) = kr0;
    *reinterpret_cast<short8*>(&Ks[buf][(krow + 32) * LDK + kcol]) = kr1;
#pragma unroll
    for (int e = 0; e < 8; ++e) {
      int d  = cc + e;
      int jj = rr ^ (((d >> 3) & 7) << 3);
      unsigned int pk = (unsigned short)vr0[e] |
                        ((unsigned int)(unsigned short)vr1[e] << 16);
      *reinterpret_cast<unsigned int*>(&Vt[buf][d * LDK + jj]) = pk;
    }
  };

  float m = -1e30f, l = 0.f;
  floatx4 oacc[4] = {};

  auto step = [&](int tt, int buf, floatx4 (&br)[4]) {
    if (tt + 1 < tt1) issue_kv(tt + 1);
    __syncthreads();   // buf published by previous step's writeKV

    floatx4 s[4];
#pragma unroll
    for (int jt = 0; jt < 4; ++jt) s[jt] = br[jt];   // waits bias loads
    if (tt + 2 < tt1) issue_bias(tt + 2, br);        // distance-2 prefetch

    // S += K Q^T  (A=K frag, B=Q frag)
#pragma unroll
    for (int jt = 0; jt < 4; ++jt) {
      short8 kf0 = *reinterpret_cast<const short8*>(
          &Ks[buf][(jt * 16 + l15) * LDK + lhi * 8]);
      short8 kf1 = *reinterpret_cast<const short8*>(
          &Ks[buf][(jt * 16 + l15) * LDK + lhi * 8 + 32]);
      s[jt] = mfma16(kf0, qf0, s[jt]);
      s[jt] = mfma16(kf1, qf1, s[jt]);
    }

    if (tt == qt) {   // diagonal tile: causal mask, kv-local > q-local
#pragma unroll
      for (int jt = 0; jt < 4; ++jt)
#pragma unroll
        for (int r = 0; r < 4; ++r) {
          int jloc = jt * 16 + lhi * 4 + r;
          if (jloc > w * 16 + l15) s[jt][r] = -1e30f;
        }
    }

    // ---- online softmax: lane-local over 16 values + 2 shfl ----
    float mx = s[0][0];
#pragma unroll
    for (int jt = 0; jt < 4; ++jt)
#pragma unroll
      for (int r = 0; r < 4; ++r) mx = fmaxf(mx, s[jt][r]);
    mx = fmaxf(mx, __shfl_xor(mx, 16));
    mx = fmaxf(mx, __shfl_xor(mx, 32));
    float mnew = fmaxf(m, mx);
    float fac  = __expf(m - mnew);
    m = mnew;
    float ps = 0.f;
#pragma unroll
    for (int jt = 0; jt < 4; ++jt)
#pragma unroll
      for (int r = 0; r < 4; ++r) {
        float pv = __expf(s[jt][r] - mnew);
        s[jt][r] = pv;
        ps += pv;
      }
    ps += __shfl_xor(ps, 16);
    ps += __shfl_xor(ps, 32);
    l = l * fac + ps;

    // transpose fac to oacc row layout (q-row = lhi*4+r)
    float facr[4];
#pragma unroll
    for (int r = 0; r < 4; ++r)
      facr[r] = __shfl(fac, (lane & 48) | (lhi * 4 + r));
#pragma unroll
    for (int dt = 0; dt < 4; ++dt)
#pragma unroll
      for (int r = 0; r < 4; ++r) oacc[dt][r] *= facr[r];

    // P -> LDS: packed 4 kv per write (wave-private rows)
#pragma unroll
    for (int jt = 0; jt < 4; ++jt) {
      short4v pv4;
      pv4.x = f2h(s[jt][0]); pv4.y = f2h(s[jt][1]);
      pv4.z = f2h(s[jt][2]); pv4.w = f2h(s[jt][3]);
      *reinterpret_cast<short4v*>(
          &Ps[(w * 16 + l15) * LDK + jt * 16 + lhi * 4]) = pv4;
    }

    // O += P V
#pragma unroll
    for (int jc = 0; jc < 2; ++jc) {
      short8 pf = *reinterpret_cast<const short8*>(
          &Ps[(w * 16 + l15) * LDK + lhi * 8 + jc * 32]);
#pragma unroll
      for (int dt = 0; dt < 4; ++dt) {
        int dd = dt * 16 + l15;
        int jj = (lhi * 8 + jc * 32) ^ (((dd >> 3) & 7) << 3);
        short8 vf = *reinterpret_cast<const short8*>(&Vt[buf][dd * LDK + jj]);
        oacc[dt] = mfma16(pf, vf, oacc[dt]);
      }
    }

    if (tt + 1 < tt1) writeKV(buf ^ 1);   // safe: nobody reads buf^1 this step
  };

  floatx4 brA[4], brB[4];
  issue_kv(tt0);
  issue_bias(tt0, brA);
  if (tt0 + 1 < tt1) issue_bias(tt0 + 1, brB);
  writeKV(0);

  int nt = tt1 - tt0;
  for (int i = 0; i < nt; i += 2) {
    step(tt0 + i, 0, brA);
    if (i + 1 < nt) step(tt0 + i + 1, 1, brB);
  }

  // ---- partial epilogue (fp16 O, fp32 m/l) ----
  size_t p = (size_t)(b * HEADS + h) * 80 + id;
  short* Ob = Opart + p * 4096;
#pragma unroll
  for (int dt = 0; dt < 4; ++dt)
#pragma unroll
    for (int r = 0; r < 4; ++r)
      Ob[(w * 16 + lhi * 4 + r) * 64 + dt * 16 + l15] = f2h(oacc[dt][r]);
  if (lhi == 0) {
    mlpart[p * 128 + w * 16 + l15] = m;
    mlpart[p * 128 + 64 + w * 16 + l15] = l;
  }
}

// ---------------- combine 1..4 partials per q-tile -------------------------
__global__ __launch_bounds__(256) void attn_combine(const short* __restrict__ Opart,
                                                    const float* __restrict__ mlpart,
                                                    short* __restrict__ o) {
  int qt = blockIdx.x, h = blockIdx.y, b = blockIdx.z;
  int nc = qt / 8 + 1;
  int t = threadIdx.x, row = t >> 2, cg = (t & 3) << 4;
  size_t base = (size_t)(b * HEADS + h) * 80;
  const int idtab[4] = {31, 63, 87, 103};

  float M = -1e30f;
  float mv0 = 0, mv1 = 0, mv2 = 0, mv3 = 0, lv0 = 0, lv1 = 0, lv2 = 0, lv3 = 0;
  {
    size_t p = base + idtab[0] - qt;
    mv0 = mlpart[p * 128 + row]; lv0 = mlpart[p * 128 + 64 + row];
    M = mv0;
  }
  if (nc > 1) { size_t p = base + idtab[1] - qt;
    mv1 = mlpart[p * 128 + row]; lv1 = mlpart[p * 128 + 64 + row]; M = fmaxf(M, mv1); }
  if (nc > 2) { size_t p = base + idtab[2] - qt;
    mv2 = mlpart[p * 128 + row]; lv2 = mlpart[p * 128 + 64 + row]; M = fmaxf(M, mv2); }
  if (nc > 3) { size_t p = base + idtab[3] - qt;
    mv3 = mlpart[p * 128 + row]; lv3 = mlpart[p * 128 + 64 + row]; M = fmaxf(M, mv3); }

  float acc[16] = {};
  float lsum = 0.f;
#pragma unroll
  for (int c2 = 0; c2 < 4; ++c2) {
    if (c2 >= nc) break;
    float mc = (c2 == 0) ? mv0 : (c2 == 1) ? mv1 : (c2 == 2) ? mv2 : mv3;
    float lc = (c2 == 0) ? lv0 : (c2 == 1) ? lv1 : (c2 == 2) ? lv2 : lv3;
    float wgt = __expf(mc - M);
    lsum += wgt * lc;
    size_t p = base + idtab[c2] - qt;
    const short8* Or =
        reinterpret_cast<const short8*>(Opart + p * 4096 + row * 64 + cg);
    short8 a0 = Or[0], a1 = Or[1];
#pragma unroll
    for (int e = 0; e < 8; ++e) {
      acc[e]     += wgt * h2f(a0[e]);
      acc[8 + e] += wgt * h2f(a1[e]);
    }
  }
  float inv = 1.f / lsum;
  short* op = o + ((size_t)(b * NSEQ + qt * 64 + row)) * INNER + h * DHEAD + cg;
  short8 o0, o1;
#pragma unroll
  for (int e = 0; e < 8; ++e) {
    o0[e] = f2h(acc[e] * inv);
    o1[e] = f2h(acc[8 + e] * inv);
  }
  reinterpret_cast<short8*>(op)[0] = o0;
  reinterpret_cast<short8*>(op)[1] = o1;
}

// ---------------------------------------------------------------------------
extern "C" void kernel_launch(void* const* d_in, const int* in_sizes, int n_in,
                              void* d_out, int out_size, void* d_ws, size_t ws_size,
                              hipStream_t stream) {
  const float* x     = (const float*)d_in[0];
  const float* bias  = (const float*)d_in[1];
  const float* gamma = (const float*)d_in[2];
  const float* beta  = (const float*)d_in[3];
  const float* wq    = (const float*)d_in[4];
  const float* wkv   = (const float*)d_in[5];
  const float* wo    = (const float*)d_in[6];
  float* out = (float*)d_out;   // fp32 output

  char* ws = (char*)d_ws;
  const size_t MB = 1024 * 1024;
  short* xn      = (short*)(ws);              // 8 MB  [4096][1024]
  short* wqkv_t  = (short*)(ws + 8  * MB);    // 6 MB  [3072][1024]
  short* wo_t    = (short*)(ws + 14 * MB);    // 2 MB  [1024][1024]
  short* qkv     = (short*)(ws + 16 * MB);    // 24 MB [4096][3072]
  short* Opart   = (short*)(ws + 40 * MB);    // 20 MB [2560][64][64] fp16
  float* mlpart  = (float*)(ws + 60 * MB);    // 1.25 MB [2560][128]
  short* ao      = xn;                        // reuse xn after qkv GEMM

  ln_kernel<<<MROWS, 256, 0, stream>>>(x, gamma, beta, xn);
  transpose_f16<<<dim3(INNER / 32, DIM / 32), 256, 0, stream>>>(wq, wqkv_t, DIM, INNER);
  transpose_f16<<<dim3(2 * INNER / 32, DIM / 32), 256, 0, stream>>>(
      wkv, wqkv_t + (size_t)1024 * 1024, DIM, 2 * INNER);
  transpose_f16<<<dim3(DIM / 32, INNER / 32), 256, 0, stream>>>(wo, wo_t, INNER, DIM);

  // fused q|kv projection: cols < 1024 get the q scale 0.125
  gemm_bt<false><<<dim3(MROWS / 128, QS / 128), 256, 0, stream>>>(
      xn, wqkv_t, qkv, QS, DIM, 0.125f, 1.0f, 1024);

  attn_kernel<<<dim3(80, HEADS, NB), 256, 0, stream>>>(qkv, bias, Opart, mlpart);
  attn_combine<<<dim3(32, HEADS, NB), 256, 0, stream>>>(Opart, mlpart, ao);

  gemm_bt<true><<<dim3(MROWS / 128, DIM / 128), 256, 0, stream>>>(
      ao, wo_t, out, DIM, INNER, 1.0f, 1.0f, 0);
}